// Round 1
// baseline (122.613 us; speedup 1.0000x reference)
//
#include <hip/hip_runtime.h>
#include <hip/hip_bf16.h>

// Problem constants
#define B_TOT  1024
#define IN_DIM 512
#define C_DIM  128
#define HID    128
#define EMB    32

#define BM  128              // rows of B per block
#define BK  64               // K-step for GEMM1
#define NKT (IN_DIM / BK)    // 8

// LDS leading dims (elements). 68 = BK+4 -> row stride 136B (8B aligned,
// 34 dwords: frag reads land 2-way-or-better on banks). 132 = HID+4.
#define XS_LD 68
#define W1_LD 68
#define HS_LD 132
#define W2_LD 132

using bf16x8 = __attribute__((ext_vector_type(8))) short;
using f32x4  = __attribute__((ext_vector_type(4))) float;

__device__ __forceinline__ unsigned short f2b(float f) {
    union { __hip_bfloat16 h; unsigned short u; } cv;
    cv.h = __float2bfloat16(f);
    return cv.u;
}
__device__ __forceinline__ unsigned int pack2(float a, float b) {
    return (unsigned int)f2b(a) | ((unsigned int)f2b(b) << 16);
}
__device__ __forceinline__ unsigned long long pack4(float a, float b, float c, float d) {
    unsigned long long lo = pack2(a, b);
    unsigned long long hi = pack2(c, d);
    return lo | (hi << 32);
}
// two ds_read_b64 (rows are 8B- but not 16B-aligned due to +4 pad)
__device__ __forceinline__ bf16x8 load8(const unsigned short* p) {
    union { unsigned long long q[2]; bf16x8 v; } u;
    u.q[0] = *(const unsigned long long*)(p);
    u.q[1] = *(const unsigned long long*)(p + 4);
    return u.v;
}

__global__ __launch_bounds__(256, 2) void bank_fused(
    const float* __restrict__ x,
    const float* __restrict__ pW1, const float* __restrict__ pb1,
    const float* __restrict__ pW2, const float* __restrict__ pb2,
    const float* __restrict__ nW1, const float* __restrict__ nb1,
    const float* __restrict__ nW2, const float* __restrict__ nb2,
    float* __restrict__ out)
{
    __shared__ unsigned short Xs [BM ][XS_LD];   // X tile, bf16, [b][k]
    __shared__ unsigned short W1T[HID][W1_LD];   // W1 tile transposed, [h][k]
    __shared__ unsigned short Hs [BM ][HS_LD];   // relu(h) tile, [b][h]
    __shared__ unsigned short W2T[EMB][W2_LD];   // W2 transposed, [e][h]

    // --- XCD-aware decode: physical p -> (c, btile, bank) such that all 128
    // c-blocks of one (btile,bank) run on ONE XCD (output-line L2 merge), and
    // consecutive ranks are consecutive c (temporal merge window).
    int p    = blockIdx.x;
    int xcd  = p & 7;
    int rank = p >> 3;               // 0..255
    int l    = xcd * 256 + rank;     // bijective 0..2047
    int c    = l & 127;
    int u    = l >> 7;               // 0..15
    int bank = u & 1;
    int btile = u >> 1;              // == xcd
    int bbase = btile * BM;

    const float* W1 = bank ? nW1 : pW1;
    const float* b1 = bank ? nb1 : pb1;
    const float* W2 = bank ? nW2 : pW2;
    const float* b2 = bank ? nb2 : pb2;
    const float* W1c = W1 + (size_t)c * IN_DIM * HID;
    const float* b1c = b1 + c * HID;
    const float* W2c = W2 + (size_t)c * HID * EMB;
    const float* b2c = b2 + c * EMB;
    float* outb = out + (size_t)bank * B_TOT * EMB * C_DIM;

    int t    = threadIdx.x;
    int wave = t >> 6;
    int lane = t & 63;
    int lr   = lane & 15;      // fragment row/col within 16
    int lkg  = lane >> 4;      // k-group 0..3
    int wm   = wave >> 1;      // wave M index (0..1)
    int wn   = wave & 1;       // wave N index (0..1)

    // --- stage W2 transposed (once per block): 32x8 groups of 4x4
    {
        int eg = t & 7, hg = t >> 3;        // e0=4*eg, h0=4*hg
        int e0 = eg * 4, h0 = hg * 4;
        f32x4 L0 = *(const f32x4*)&W2c[(h0 + 0) * EMB + e0];
        f32x4 L1 = *(const f32x4*)&W2c[(h0 + 1) * EMB + e0];
        f32x4 L2 = *(const f32x4*)&W2c[(h0 + 2) * EMB + e0];
        f32x4 L3 = *(const f32x4*)&W2c[(h0 + 3) * EMB + e0];
#pragma unroll
        for (int j = 0; j < 4; ++j) {
            *(unsigned long long*)&W2T[e0 + j][h0] = pack4(L0[j], L1[j], L2[j], L3[j]);
        }
    }

    // bias fragments (per-lane scalars)
    float b1v[4];
#pragma unroll
    for (int ni = 0; ni < 4; ++ni) b1v[ni] = b1c[wn * 64 + ni * 16 + lr];
    float b2v[2];
#pragma unroll
    for (int ei = 0; ei < 2; ++ei) b2v[ei] = b2c[ei * 16 + lr];

    f32x4 acc[4][4];
#pragma unroll
    for (int mi = 0; mi < 4; ++mi)
#pragma unroll
        for (int ni = 0; ni < 4; ++ni) acc[mi][ni] = (f32x4){0.f, 0.f, 0.f, 0.f};

    // ================= GEMM1: H = relu(X * W1 + b1), K = 512 =================
    for (int kt = 0; kt < NKT; ++kt) {
        int kb = kt * BK;

        // stage X tile [128][64]: 2048 float4s, 8 per thread, straight layout
#pragma unroll
        for (int w8 = 0; w8 < 8; ++w8) {
            int f   = w8 * 256 + t;
            int row = f >> 4;
            int col = (f & 15) * 4;
            f32x4 v = *(const f32x4*)&x[(size_t)(bbase + row) * IN_DIM + kb + col];
            *(unsigned long long*)&Xs[row][col] = pack4(v[0], v[1], v[2], v[3]);
        }
        // stage W1 tile [64][128] transposed -> W1T[h][k]: 512 4x4 groups
#pragma unroll
        for (int g = 0; g < 2; ++g) {
            int s  = g * 256 + t;
            int kg = s >> 5;          // 0..15
            int hg = s & 31;          // 0..31
            int k0 = kg * 4, h0 = hg * 4;
            const float* src = &W1c[(size_t)(kb + k0) * HID + h0];
            f32x4 L0 = *(const f32x4*)(src + 0 * HID);
            f32x4 L1 = *(const f32x4*)(src + 1 * HID);
            f32x4 L2 = *(const f32x4*)(src + 2 * HID);
            f32x4 L3 = *(const f32x4*)(src + 3 * HID);
#pragma unroll
            for (int j = 0; j < 4; ++j) {
                *(unsigned long long*)&W1T[h0 + j][k0] = pack4(L0[j], L1[j], L2[j], L3[j]);
            }
        }
        __syncthreads();

        // compute: 2 k-frags x (4 m-tiles x 4 n-tiles) MFMAs per wave
#pragma unroll
        for (int ki = 0; ki < 2; ++ki) {
            int kcol = ki * 32 + lkg * 8;
            bf16x8 af[4], bfr[4];
#pragma unroll
            for (int mi = 0; mi < 4; ++mi)
                af[mi] = load8(&Xs[wm * 64 + mi * 16 + lr][kcol]);
#pragma unroll
            for (int ni = 0; ni < 4; ++ni)
                bfr[ni] = load8(&W1T[wn * 64 + ni * 16 + lr][kcol]);
#pragma unroll
            for (int mi = 0; mi < 4; ++mi)
#pragma unroll
                for (int ni = 0; ni < 4; ++ni)
                    acc[mi][ni] = __builtin_amdgcn_mfma_f32_16x16x32_bf16(
                        af[mi], bfr[ni], acc[mi][ni], 0, 0, 0);
        }
        __syncthreads();
    }

    // --- epilogue1: bias + relu + bf16 -> Hs[b][h]
#pragma unroll
    for (int mi = 0; mi < 4; ++mi) {
        int row = wm * 64 + mi * 16 + lkg * 4;
#pragma unroll
        for (int ni = 0; ni < 4; ++ni) {
            int col = wn * 64 + ni * 16 + lr;
#pragma unroll
            for (int j = 0; j < 4; ++j) {
                float v = acc[mi][ni][j] + b1v[ni];
                v = fmaxf(v, 0.f);
                Hs[row + j][col] = f2b(v);
            }
        }
    }
    __syncthreads();

    // ================= GEMM2: out = H * W2 + b2 (M=128,N=32,K=128) ==========
    f32x4 acc2[2][2];
#pragma unroll
    for (int m2 = 0; m2 < 2; ++m2)
#pragma unroll
        for (int ei = 0; ei < 2; ++ei) acc2[m2][ei] = (f32x4){0.f, 0.f, 0.f, 0.f};

    int rb = wave * 32;   // each wave owns 32 rows
#pragma unroll
    for (int k2 = 0; k2 < 4; ++k2) {
        int kcol = k2 * 32 + lkg * 8;
        bf16x8 a2[2], b2f[2];
#pragma unroll
        for (int m2 = 0; m2 < 2; ++m2)
            a2[m2] = load8(&Hs[rb + m2 * 16 + lr][kcol]);
#pragma unroll
        for (int ei = 0; ei < 2; ++ei)
            b2f[ei] = load8(&W2T[ei * 16 + lr][kcol]);
#pragma unroll
        for (int m2 = 0; m2 < 2; ++m2)
#pragma unroll
            for (int ei = 0; ei < 2; ++ei)
                acc2[m2][ei] = __builtin_amdgcn_mfma_f32_16x16x32_bf16(
                    a2[m2], b2f[ei], acc2[m2][ei], 0, 0, 0);
    }

    // --- epilogue2: bias + store out[b][e][c] (fp32, strided by C)
#pragma unroll
    for (int m2 = 0; m2 < 2; ++m2) {
#pragma unroll
        for (int ei = 0; ei < 2; ++ei) {
            int e = ei * 16 + lr;
#pragma unroll
            for (int j = 0; j < 4; ++j) {
                int brow = bbase + rb + m2 * 16 + lkg * 4 + j;
                float v = acc2[m2][ei][j] + b2v[ei];
                outb[((size_t)brow * EMB + e) * C_DIM + c] = v;
            }
        }
    }
}

extern "C" void kernel_launch(void* const* d_in, const int* in_sizes, int n_in,
                              void* d_out, int out_size, void* d_ws, size_t ws_size,
                              hipStream_t stream) {
    const float* x   = (const float*)d_in[0];
    const float* pW1 = (const float*)d_in[1];
    const float* pb1 = (const float*)d_in[2];
    const float* pW2 = (const float*)d_in[3];
    const float* pb2 = (const float*)d_in[4];
    const float* nW1 = (const float*)d_in[5];
    const float* nb1 = (const float*)d_in[6];
    const float* nW2 = (const float*)d_in[7];
    const float* nb2 = (const float*)d_in[8];
    float* out = (float*)d_out;

    bank_fused<<<dim3(2048), dim3(256), 0, stream>>>(
        x, pW1, pb1, pW2, pb2, nW1, nb1, nW2, nb2, out);
}